// Round 4
// baseline (1004.010 us; speedup 1.0000x reference)
//
#include <hip/hip_runtime.h>

// GraphRec VC_Aggregator, fp32 baseline.
// B=4096, L=50, D=128. One workgroup per b, 320 threads (5 waves).
// Per-thread register tile: 5 l x 4 d. K staged in 16-wide chunks.

#define NTHR 320
#define TL 5
#define TD 4

__device__ __forceinline__ float relu_f(float x) { return x > 0.f ? x : 0.f; }

// acc[TL][TD] += src(50 x K) * Wg(128 x K)^T, K = nChunk*16.
// Wg rows are wStride floats apart. If srcFull==nullptr, source is the
// gathered embedding concat [c2e(hvc) | r2e(hr)] staged chunk-by-chunk.
__device__ __forceinline__ void gemm_phase(
    float acc[TL][TD],
    const float* __restrict__ Wg, int wStride, int nChunk,
    const float* __restrict__ srcFull,
    const int* __restrict__ ivc, const int* __restrict__ ir,
    const float* __restrict__ c2e, const float* __restrict__ r2e,
    float* __restrict__ Echunk, float* __restrict__ Wchunk,
    int tid, int l0, int d0)
{
#pragma unroll
  for (int i = 0; i < TL; ++i)
#pragma unroll
    for (int j = 0; j < TD; ++j) acc[i][j] = 0.f;

  for (int c = 0; c < nChunk; ++c) {
    const int k0 = c * 16;
    __syncthreads();
    // Stage W^T chunk: Wchunk[k][d] = Wg[d][k0+k], k<16.
    // Global reads: 4 consecutive lanes cover 64B contiguous -> coalesced, L2-hit.
    for (int i = tid; i < 512; i += NTHR) {
      const int r = i & 3, d = i >> 2;
      const float4 v = *(const float4*)(Wg + (size_t)d * wStride + k0 + 4 * r);
      Wchunk[(4 * r + 0) * 128 + d] = v.x;
      Wchunk[(4 * r + 1) * 128 + d] = v.y;
      Wchunk[(4 * r + 2) * 128 + d] = v.z;
      Wchunk[(4 * r + 3) * 128 + d] = v.w;
    }
    if (srcFull == nullptr) {
      // Stage embedding chunk: E[l][k] for k in [k0, k0+16)
      for (int i = tid; i < 200; i += NTHR) {
        const int r = i & 3, l = i >> 2;
        const float* row;
        int col;
        if (k0 < 128) { row = c2e + (size_t)ivc[l] * 128; col = k0 + 4 * r; }
        else          { row = r2e + (size_t)ir[l] * 128;  col = k0 - 128 + 4 * r; }
        *(float4*)(Echunk + l * 16 + 4 * r) = *(const float4*)(row + col);
      }
    }
    __syncthreads();

    const float* sp = srcFull ? (srcFull + k0) : Echunk;
    const int ss = srcFull ? 128 : 16;
#pragma unroll
    for (int kk = 0; kk < 4; ++kk) {
      float w[4][4];  // [q over k][j over d]
#pragma unroll
      for (int q = 0; q < 4; ++q) {
        const float4 t = *(const float4*)(Wchunk + (kk * 4 + q) * 128 + d0);
        w[q][0] = t.x; w[q][1] = t.y; w[q][2] = t.z; w[q][3] = t.w;
      }
#pragma unroll
      for (int i = 0; i < TL; ++i) {
        const float4 t = *(const float4*)(sp + (l0 + i) * ss + kk * 4);
        const float e0 = t.x, e1 = t.y, e2 = t.z, e3 = t.w;
#pragma unroll
        for (int j = 0; j < TD; ++j) {
          acc[i][j] = fmaf(e0, w[0][j], acc[i][j]);
          acc[i][j] = fmaf(e1, w[1][j], acc[i][j]);
          acc[i][j] = fmaf(e2, w[2][j], acc[i][j]);
          acc[i][j] = fmaf(e3, w[3][j], acc[i][j]);
        }
      }
    }
  }
}

__global__ __launch_bounds__(NTHR, 2)
void vc_agg_kernel(const int* __restrict__ nodes,
                   const int* __restrict__ hvc,
                   const int* __restrict__ hr,
                   const float* __restrict__ c2e,
                   const float* __restrict__ v2e,
                   const float* __restrict__ r2e,
                   const float* __restrict__ w1, const float* __restrict__ b1,
                   const float* __restrict__ w2, const float* __restrict__ b2,
                   const float* __restrict__ a1w, const float* __restrict__ a1b,
                   const float* __restrict__ a2w, const float* __restrict__ a2b,
                   const float* __restrict__ a3w,
                   float* __restrict__ out)
{
  __shared__ float Xbuf[50 * 128];        // x / a1 (aliased), also ppu scratch
  __shared__ float Obuf[50 * 128];        // o_history
  __shared__ float stageF[800 + 2048];    // Echunk(800) + Wchunk(2048); aliases plbuf/psum
  __shared__ float ubuf[128], pu[128];
  __shared__ float logits[64], wbuf[64];
  __shared__ int ivc[50], ir[50];

  float* Echunk = stageF;
  float* Wchunk = stageF + 800;
  float* plbuf = stageF;          // [50][32]
  float* psum = stageF + 1600;    // [2][128]

  const int tid = threadIdx.x;
  const int b = blockIdx.x;
  const int lg = tid / 32, dg = tid & 31;
  const int l0 = lg * TL, d0 = dg * TD;

  if (tid < 50) { ivc[tid] = hvc[b * 50 + tid]; ir[tid] = hr[b * 50 + tid]; }
  if (tid < 128) ubuf[tid] = v2e[(size_t)nodes[b] * 128 + tid];
  __syncthreads();

  // pu[d] = a1b[d] + sum_k ubuf[k] * a1w[d][128+k]  (l-invariant half of att1)
  {
    float* ppu = Xbuf;  // [128][32] scratch (X not live yet)
    for (int i = tid; i < 4096; i += NTHR) {
      const int r = i & 31, d = i >> 5;
      const float4 wv = *(const float4*)(a1w + (size_t)d * 256 + 128 + 4 * r);
      const float4 uv = *(const float4*)(ubuf + 4 * r);
      ppu[i] = wv.x * uv.x + wv.y * uv.y + wv.z * uv.z + wv.w * uv.w;
    }
    __syncthreads();
    if (tid < 128) {
      float s = a1b[tid];
#pragma unroll
      for (int r = 0; r < 32; ++r) s += ppu[tid * 32 + r];
      pu[tid] = s;
    }
    __syncthreads();
  }

  float acc[TL][TD];

  // x = relu(E @ w1^T + b1)   (K=256, E gathered chunk-wise)
  gemm_phase(acc, w1, 256, 16, nullptr, ivc, ir, c2e, r2e, Echunk, Wchunk, tid, l0, d0);
  {
    const float4 bb = *(const float4*)(b1 + d0);
#pragma unroll
    for (int i = 0; i < TL; ++i) {
      float4 v;
      v.x = relu_f(acc[i][0] + bb.x);
      v.y = relu_f(acc[i][1] + bb.y);
      v.z = relu_f(acc[i][2] + bb.z);
      v.w = relu_f(acc[i][3] + bb.w);
      *(float4*)(Xbuf + (l0 + i) * 128 + d0) = v;
    }
  }

  // o = relu(x @ w2^T + b2)   (K=128)
  gemm_phase(acc, w2, 128, 8, Xbuf, ivc, ir, c2e, r2e, Echunk, Wchunk, tid, l0, d0);
  {
    const float4 bb = *(const float4*)(b2 + d0);
#pragma unroll
    for (int i = 0; i < TL; ++i) {
      float4 v;
      v.x = relu_f(acc[i][0] + bb.x);
      v.y = relu_f(acc[i][1] + bb.y);
      v.z = relu_f(acc[i][2] + bb.z);
      v.w = relu_f(acc[i][3] + bb.w);
      *(float4*)(Obuf + (l0 + i) * 128 + d0) = v;
    }
  }

  // a1 = relu(o @ a1w[:, :128]^T + pu)   (K=128; u-half folded into pu)
  gemm_phase(acc, a1w, 256, 8, Obuf, ivc, ir, c2e, r2e, Echunk, Wchunk, tid, l0, d0);
  {
    float pv[TD];
#pragma unroll
    for (int j = 0; j < TD; ++j) pv[j] = pu[d0 + j];
#pragma unroll
    for (int i = 0; i < TL; ++i) {
      float4 v;
      v.x = relu_f(acc[i][0] + pv[0]);
      v.y = relu_f(acc[i][1] + pv[1]);
      v.z = relu_f(acc[i][2] + pv[2]);
      v.w = relu_f(acc[i][3] + pv[3]);
      *(float4*)(Xbuf + (l0 + i) * 128 + d0) = v;
    }
  }

  // a2 = relu(a1 @ a2w^T + a2b); logits = a2 @ a3w  (fused, a2 never materialized)
  gemm_phase(acc, a2w, 128, 8, Xbuf, ivc, ir, c2e, r2e, Echunk, Wchunk, tid, l0, d0);
  __syncthreads();  // stage region reads done -> safe to overwrite with plbuf
  {
    const float4 bb = *(const float4*)(a2b + d0);
    const float4 w3 = *(const float4*)(a3w + d0);
#pragma unroll
    for (int i = 0; i < TL; ++i) {
      float s = relu_f(acc[i][0] + bb.x) * w3.x;
      s = fmaf(relu_f(acc[i][1] + bb.y), w3.y, s);
      s = fmaf(relu_f(acc[i][2] + bb.z), w3.z, s);
      s = fmaf(relu_f(acc[i][3] + bb.w), w3.w, s);
      plbuf[(l0 + i) * 32 + dg] = s;
    }
  }
  __syncthreads();
  if (tid < 50) {
    float s = 0.f;
#pragma unroll
    for (int g = 0; g < 32; ++g) s += plbuf[tid * 32 + g];
    logits[tid] = s;  // att3_b is a constant shift -> softmax-invariant
  }
  __syncthreads();

  // softmax over L=50 (wave 0)
  if (tid < 64) {
    float x = (tid < 50) ? logits[tid] : -3.4e38f;
#pragma unroll
    for (int off = 32; off; off >>= 1) x = fmaxf(x, __shfl_xor(x, off));
    float e = (tid < 50) ? __expf(logits[tid] - x) : 0.f;
    float s = e;
#pragma unroll
    for (int off = 32; off; off >>= 1) s += __shfl_xor(s, off);
    if (tid < 50) wbuf[tid] = e / s;
  }
  __syncthreads();

  // out[b][d] = sum_l wbuf[l] * o[l][d]
  if (tid < 256) {
    const int d = tid & 127, lh = tid >> 7;
    float s = 0.f;
    for (int l = lh * 25; l < lh * 25 + 25; ++l) s = fmaf(wbuf[l], Obuf[l * 128 + d], s);
    psum[lh * 128 + d] = s;
  }
  __syncthreads();
  if (tid < 128) out[(size_t)b * 128 + tid] = psum[tid] + psum[128 + tid];
}

extern "C" void kernel_launch(void* const* d_in, const int* in_sizes, int n_in,
                              void* d_out, int out_size, void* d_ws, size_t ws_size,
                              hipStream_t stream) {
  const int* nodes = (const int*)d_in[0];
  const int* hvc   = (const int*)d_in[1];
  const int* hr    = (const int*)d_in[2];
  const float* c2e = (const float*)d_in[3];
  const float* v2e = (const float*)d_in[4];
  const float* r2e = (const float*)d_in[5];
  const float* w1  = (const float*)d_in[6];
  const float* b1  = (const float*)d_in[7];
  const float* w2  = (const float*)d_in[8];
  const float* b2  = (const float*)d_in[9];
  const float* a1w = (const float*)d_in[10];
  const float* a1b = (const float*)d_in[11];
  const float* a2w = (const float*)d_in[12];
  const float* a2b = (const float*)d_in[13];
  const float* a3w = (const float*)d_in[14];
  float* out = (float*)d_out;

  vc_agg_kernel<<<4096, NTHR, 0, stream>>>(nodes, hvc, hr, c2e, v2e, r2e,
                                           w1, b1, w2, b2, a1w, a1b, a2w, a2b, a3w, out);
}

// Round 5
// 274.271 us; speedup vs baseline: 3.6606x; 3.6606x over previous
//
#include <hip/hip_runtime.h>

// GraphRec VC_Aggregator — bf16 MFMA version.
// B=4096, L=50 (pad 64), D=128. Grid 256 blocks (1/CU), 512 thr (8 waves),
// 16 b's per block. Weights register-resident as bf16 MFMA B-fragments.
// Activations in LDS bf16, XOR-swizzled (byte ^= (row&7)<<4) for
// conflict-free ds_read_b128 A-fragments. Phase3 A = [O | u] (K=256) folds
// the l-invariant att1 half exactly. Phase4 fuses att2+att3 -> logits.

#define NB 16
#define NTHR 512

typedef __attribute__((ext_vector_type(8))) short short8;   // 8 bf16 (4 VGPR)
typedef __attribute__((ext_vector_type(4))) float f32x4;

__device__ __forceinline__ float relu_f(float x) { return x > 0.f ? x : 0.f; }

__device__ __forceinline__ short f2bf(float f) {  // RNE float->bf16 bits
  union { float f; unsigned u; } v; v.f = f;
  unsigned r = v.u + 0x7FFFu + ((v.u >> 16) & 1u);
  return (short)(r >> 16);
}

__device__ __forceinline__ short8 cvt8(float4 a, float4 b) {
  short8 r;
  r[0] = f2bf(a.x); r[1] = f2bf(a.y); r[2] = f2bf(a.z); r[3] = f2bf(a.w);
  r[4] = f2bf(b.x); r[5] = f2bf(b.y); r[6] = f2bf(b.z); r[7] = f2bf(b.w);
  return r;
}

// Weight B-fragment: lane holds W[d = n0+(lane&15)][k0 + (lane>>4)*8 + e]
__device__ __forceinline__ short8 wfrag(const float* __restrict__ W, int ldk,
                                        int d, int k) {
  const float4* p = (const float4*)(W + (size_t)d * ldk + k);
  return cvt8(p[0], p[1]);
}

// A-fragments from swizzled LDS; acc[mt] over 4 M-tiles (rows mt*16+..).
template <int NS, int ROWB>
__device__ __forceinline__ void run_phase(const char* __restrict__ Abase,
                                          const short8* wf, f32x4 acc[4],
                                          int r16, int kg) {
#pragma unroll
  for (int mt = 0; mt < 4; ++mt) acc[mt] = (f32x4){0.f, 0.f, 0.f, 0.f};
#pragma unroll
  for (int s = 0; s < NS; ++s) {
    const int kb = s * 64 + kg * 16;  // byte offset of this frag's k-start
#pragma unroll
    for (int mt = 0; mt < 4; ++mt) {
      const int row = mt * 16 + r16;
      short8 a = *(const short8*)(Abase + row * ROWB + (kb ^ ((row & 7) << 4)));
      acc[mt] = __builtin_amdgcn_mfma_f32_16x16x32_bf16(a, wf[s], acc[mt], 0, 0, 0);
    }
  }
}

__global__ __launch_bounds__(NTHR, 2)
void vc_agg_kernel(const int* __restrict__ nodes,
                   const int* __restrict__ hvc,
                   const int* __restrict__ hr,
                   const float* __restrict__ c2e,
                   const float* __restrict__ v2e,
                   const float* __restrict__ r2e,
                   const float* __restrict__ w1, const float* __restrict__ b1,
                   const float* __restrict__ w2, const float* __restrict__ b2,
                   const float* __restrict__ a1w, const float* __restrict__ a1b,
                   const float* __restrict__ a2w, const float* __restrict__ a2b,
                   const float* __restrict__ a3w,
                   float* __restrict__ out)
{
  __shared__ __align__(16) char sA3[64 * 512];  // E (p1 A) / [O|u] (p3 A), bf16 swz
  __shared__ __align__(16) char sX[64 * 256];   // X (p2 A) / A1 (p4 A), bf16 swz
  __shared__ float sOf[64 * 132];               // O fp32, pad-132 rows
  __shared__ float sU[128];
  __shared__ int sIvc[50], sIr[50];
  __shared__ float sPlog[8 * 64];
  __shared__ float sWts[64];
  __shared__ float sPs[4 * 128];

  const int tid = threadIdx.x;
  const int w = tid >> 6;          // wave 0..7 -> N-tile (cols 16w..16w+15)
  const int lane = tid & 63;
  const int r16 = lane & 15;
  const int kg = lane >> 4;        // 0..3
  const int col = w * 16 + r16;    // this lane's output column

  // ---- one-time: register-resident weight fragments (bf16) + scalars ----
  short8 wf1[8], wf2[4], wfa1[8], wfa2[4];
#pragma unroll
  for (int s = 0; s < 8; ++s) wf1[s] = wfrag(w1, 256, col, s * 32 + kg * 8);
#pragma unroll
  for (int s = 0; s < 4; ++s) wf2[s] = wfrag(w2, 128, col, s * 32 + kg * 8);
#pragma unroll
  for (int s = 0; s < 8; ++s) wfa1[s] = wfrag(a1w, 256, col, s * 32 + kg * 8);
#pragma unroll
  for (int s = 0; s < 4; ++s) wfa2[s] = wfrag(a2w, 128, col, s * 32 + kg * 8);
  const float b1v = b1[col], b2v = b2[col];
  const float a1bv = a1b[col], a2bv = a2b[col], a3v = a3w[col];

  const int el = tid >> 3, esub = tid & 7;  // E-stage / u-fill mapping

  for (int ib = 0; ib < NB; ++ib) {
    const int b = blockIdx.x * NB + ib;

    // ---- stage indices + u ----
    if (tid < 50) { sIvc[tid] = hvc[b * 50 + tid]; sIr[tid] = hr[b * 50 + tid]; }
    if (tid < 128) sU[tid] = v2e[(size_t)nodes[b] * 128 + tid];
    __syncthreads();

    // ---- stage E = [c2e|r2e] -> sA3 (bf16, swizzled) ----
    if (el < 50) {
      const int kk = esub * 32;  // 32 k per thread, single table per thread
      const float* src = (kk < 128) ? (c2e + (size_t)sIvc[el] * 128 + kk)
                                    : (r2e + (size_t)sIr[el] * 128 + (kk - 128));
#pragma unroll
      for (int j = 0; j < 4; ++j) {
        const float4* p = (const float4*)(src + j * 8);
        const int kb = (kk + j * 8) * 2;
        *(short8*)(sA3 + el * 512 + (kb ^ ((el & 7) << 4))) = cvt8(p[0], p[1]);
      }
    }
    __syncthreads();

    f32x4 acc[4];

    // ---- phase 1: X = relu(E @ w1^T + b1), K=256 ----
    run_phase<8, 512>(sA3, wf1, acc, r16, kg);
#pragma unroll
    for (int mt = 0; mt < 4; ++mt)
#pragma unroll
      for (int r = 0; r < 4; ++r) {
        const int row = mt * 16 + kg * 4 + r;
        *(short*)(sX + row * 256 + ((col * 2) ^ ((row & 7) << 4))) =
            f2bf(relu_f(acc[mt][r] + b1v));
      }
    __syncthreads();

    // ---- phase 2: O = relu(X @ w2^T + b2), K=128 ----
    run_phase<4, 256>(sX, wf2, acc, r16, kg);
#pragma unroll
    for (int mt = 0; mt < 4; ++mt)
#pragma unroll
      for (int r = 0; r < 4; ++r) {
        const int row = mt * 16 + kg * 4 + r;
        const float v = relu_f(acc[mt][r] + b2v);
        *(short*)(sA3 + row * 512 + ((col * 2) ^ ((row & 7) << 4))) = f2bf(v);
        sOf[row * 132 + col] = v;
      }
    // ---- fill u into cols 128..255 of sA3 (phase-3 A = [O | u]) ----
    {
      const float* up = sU + esub * 16;
#pragma unroll
      for (int m = 0; m < 2; ++m) {
        const int kb = (128 + esub * 16 + m * 8) * 2;
        *(short8*)(sA3 + el * 512 + (kb ^ ((el & 7) << 4))) =
            cvt8(*(const float4*)(up + m * 8), *(const float4*)(up + m * 8 + 4));
      }
    }
    __syncthreads();

    // ---- phase 3: A1 = relu([O|u] @ a1w^T + a1b), K=256 ----
    run_phase<8, 512>(sA3, wfa1, acc, r16, kg);
#pragma unroll
    for (int mt = 0; mt < 4; ++mt)
#pragma unroll
      for (int r = 0; r < 4; ++r) {
        const int row = mt * 16 + kg * 4 + r;
        *(short*)(sX + row * 256 + ((col * 2) ^ ((row & 7) << 4))) =
            f2bf(relu_f(acc[mt][r] + a1bv));
      }
    __syncthreads();

    // ---- phase 4: logits = relu(A1 @ a2w^T + a2b) . a3w  (fused) ----
    run_phase<4, 256>(sX, wfa2, acc, r16, kg);
    {
      float pm[4][4];
#pragma unroll
      for (int mt = 0; mt < 4; ++mt)
#pragma unroll
        for (int r = 0; r < 4; ++r) {
          float v = relu_f(acc[mt][r] + a2bv) * a3v;
#pragma unroll
          for (int off = 1; off < 16; off <<= 1) v += __shfl_xor(v, off);
          pm[mt][r] = v;  // row-sum over this wave's 16 cols
        }
      if (r16 == 0) {
#pragma unroll
        for (int mt = 0; mt < 4; ++mt)
#pragma unroll
          for (int r = 0; r < 4; ++r)
            sPlog[w * 64 + mt * 16 + kg * 4 + r] = pm[mt][r];
      }
    }
    __syncthreads();

    // ---- reduce logits over waves + softmax over L=50 (wave 0) ----
    if (tid < 64) {
      float s = 0.f;
#pragma unroll
      for (int ww = 0; ww < 8; ++ww) s += sPlog[ww * 64 + tid];
      float x = (tid < 50) ? s : -3.4e38f;
#pragma unroll
      for (int off = 32; off; off >>= 1) x = fmaxf(x, __shfl_xor(x, off));
      const float e = (tid < 50) ? __expf(s - x) : 0.f;
      float t = e;
#pragma unroll
      for (int off = 32; off; off >>= 1) t += __shfl_xor(t, off);
      if (tid < 50) sWts[tid] = e / t;
    }
    __syncthreads();

    // ---- out[b][d] = sum_l wts[l] * O[l][d]  (fp32 O) ----
    {
      const int d = tid & 127, g = tid >> 7;  // 4 row-groups
      const int lb = g * 13, le = (lb + 13 < 50) ? lb + 13 : 50;
      float s = 0.f;
      for (int l = lb; l < le; ++l) s = fmaf(sWts[l], sOf[l * 132 + d], s);
      sPs[g * 128 + d] = s;
    }
    __syncthreads();
    if (tid < 128)
      out[(size_t)b * 128 + tid] =
          sPs[tid] + sPs[128 + tid] + sPs[256 + tid] + sPs[384 + tid];
    __syncthreads();
  }
}

extern "C" void kernel_launch(void* const* d_in, const int* in_sizes, int n_in,
                              void* d_out, int out_size, void* d_ws, size_t ws_size,
                              hipStream_t stream) {
  const int* nodes = (const int*)d_in[0];
  const int* hvc   = (const int*)d_in[1];
  const int* hr    = (const int*)d_in[2];
  const float* c2e = (const float*)d_in[3];
  const float* v2e = (const float*)d_in[4];
  const float* r2e = (const float*)d_in[5];
  const float* w1  = (const float*)d_in[6];
  const float* b1  = (const float*)d_in[7];
  const float* w2  = (const float*)d_in[8];
  const float* b2  = (const float*)d_in[9];
  const float* a1w = (const float*)d_in[10];
  const float* a1b = (const float*)d_in[11];
  const float* a2w = (const float*)d_in[12];
  const float* a2b = (const float*)d_in[13];
  const float* a3w = (const float*)d_in[14];
  float* out = (float*)d_out;

  vc_agg_kernel<<<4096 / NB, NTHR, 0, stream>>>(nodes, hvc, hr, c2e, v2e, r2e,
                                                w1, b1, w2, b2, a1w, a1b, a2w,
                                                a2b, a3w, out);
}